// Round 6
// baseline (73.683 us; speedup 1.0000x reference)
//
#include <hip/hip_runtime.h>
#include <hip/hip_bf16.h>

#define BB 2
#define NN 4096
#define LL 256
#define DD 2048
#define CC 6
#define EPSF 1e-6f

typedef float floatx4 __attribute__((ext_vector_type(4)));

__device__ __forceinline__ float dot4(float4 a, float4 b) {
    return a.x * b.x + a.y * b.y + a.z * b.z + a.w * b.w;
}

// ---------------------------------------------------------------------------
// K1: cluster softmax -> cw (B,L,C). One block per (b,l) row.
__global__ __launch_bounds__(256) void k_cluster(const float* __restrict__ te,
                                                 const float* __restrict__ Wc,
                                                 float* __restrict__ cw) {
    const int tid = threadIdx.x;
    const int row = blockIdx.x;              // b*LL + l
    const float4* t4 = (const float4*)(te + (size_t)row * DD);
    float p[CC];
#pragma unroll
    for (int c = 0; c < CC; ++c) p[c] = 0.f;
#pragma unroll
    for (int it = 0; it < 2; ++it) {
        const int i = it * 256 + tid;
        const float4 xv = t4[i];
#pragma unroll
        for (int c = 0; c < CC; ++c)
            p[c] += dot4(xv, ((const float4*)(Wc + (size_t)c * DD))[i]);
    }
#pragma unroll
    for (int c = 0; c < CC; ++c)
        for (int off = 32; off; off >>= 1) p[c] += __shfl_down(p[c], off);
    __shared__ float sred[4][CC];
    const int lane = tid & 63, wid = tid >> 6;
    if (lane == 0) {
#pragma unroll
        for (int c = 0; c < CC; ++c) sred[wid][c] = p[c];
    }
    __syncthreads();
    if (tid == 0) {
        float lg[CC], m = -1e30f;
#pragma unroll
        for (int c = 0; c < CC; ++c) {
            lg[c] = sred[0][c] + sred[1][c] + sred[2][c] + sred[3][c];
            m = fmaxf(m, lg[c]);
        }
        float s = 0.f;
#pragma unroll
        for (int c = 0; c < CC; ++c) { lg[c] = __expf(lg[c] - m); s += lg[c]; }
        const float inv = 1.f / s;
#pragma unroll
        for (int c = 0; c < CC; ++c) cw[row * CC + c] = lg[c] * inv;
    }
}

// ---------------------------------------------------------------------------
// K2: concept_reps -> cr (B,C,D). 64 blocks; block = (b, 64-wide d-slice),
//     4 l-chunks across waves, LDS reduce.
__global__ __launch_bounds__(256) void k_creps(const float* __restrict__ te,
                                               const float* __restrict__ cw,
                                               float* __restrict__ cr) {
    const int tid = threadIdx.x;
    const int b = blockIdx.x >> 5;
    const int d0 = (blockIdx.x & 31) * 64;
    const int lane = tid & 63, wid = tid >> 6;
    __shared__ float scw[LL * CC];                       // 6 KB
    __shared__ float sacc[4][64][CC];                    // 6 KB
    for (int i = tid; i < LL * CC; i += 256) scw[i] = cw[b * LL * CC + i];
    __syncthreads();
    float acc[CC];
#pragma unroll
    for (int c = 0; c < CC; ++c) acc[c] = 0.f;
    const float* tb = te + ((size_t)b * LL + wid * 64) * DD + d0 + lane;
    for (int l = 0; l < 64; ++l) {
        const float xv = tb[(size_t)l * DD];
        const int gl = wid * 64 + l;
#pragma unroll
        for (int c = 0; c < CC; ++c) acc[c] = fmaf(scw[gl * CC + c], xv, acc[c]);
    }
#pragma unroll
    for (int c = 0; c < CC; ++c) sacc[wid][lane][c] = acc[c];
    __syncthreads();
    if (tid < 64) {
#pragma unroll
        for (int c = 0; c < CC; ++c) {
            const float s = sacc[0][tid][c] + sacc[1][tid][c] +
                            sacc[2][tid][c] + sacc[3][tid][c];
            cr[((size_t)b * CC + c) * DD + d0 + tid] = s;
        }
    }
}

// ---------------------------------------------------------------------------
// K3: v = cr.Wv^T + blend-softmax + unbiased-var gate -> fused (B,D).
//     128 blocks, 4 e-columns per wave (cr L2 traffic /4 vs 1e-wave).
__global__ __launch_bounds__(256) void k_vfuse(const float* __restrict__ cr,
                                               const float* __restrict__ Wv,
                                               const float* __restrict__ blendw,
                                               const float* __restrict__ sgate,
                                               const int* __restrict__ issur,
                                               float* __restrict__ fused) {
    const int tid = threadIdx.x;
    const int lane = tid & 63, wid = tid >> 6;
    const int e0 = (blockIdx.x * 4 + wid) * 4;           // wave's 4 e-columns
    float acc[BB][4][CC];
#pragma unroll
    for (int b = 0; b < BB; ++b)
#pragma unroll
        for (int j = 0; j < 4; ++j)
#pragma unroll
            for (int c = 0; c < CC; ++c) acc[b][j][c] = 0.f;
#pragma unroll
    for (int it = 0; it < 8; ++it) {
        const int d = it * 256 + lane * 4;
        float4 w[4];
#pragma unroll
        for (int j = 0; j < 4; ++j)
            w[j] = *(const float4*)(Wv + (size_t)(e0 + j) * DD + d);
#pragma unroll
        for (int b = 0; b < BB; ++b)
#pragma unroll
            for (int c = 0; c < CC; ++c) {
                const float4 cv = *(const float4*)(cr + ((size_t)b * CC + c) * DD + d);
#pragma unroll
                for (int j = 0; j < 4; ++j) acc[b][j][c] += dot4(cv, w[j]);
            }
    }
#pragma unroll
    for (int b = 0; b < BB; ++b)
#pragma unroll
        for (int j = 0; j < 4; ++j)
#pragma unroll
            for (int c = 0; c < CC; ++c)
                for (int off = 32; off; off >>= 1)
                    acc[b][j][c] += __shfl_down(acc[b][j][c], off);
    if (lane == 0) {
        float bw[CC], m = -1e30f;
#pragma unroll
        for (int c = 0; c < CC; ++c) { bw[c] = blendw[c]; m = fmaxf(m, bw[c]); }
        float s = 0.f;
#pragma unroll
        for (int c = 0; c < CC; ++c) { bw[c] = __expf(bw[c] - m); s += bw[c]; }
        const float inv = 1.f / s;
#pragma unroll
        for (int c = 0; c < CC; ++c) bw[c] *= inv;
        const float gate = 1.f / (1.f + __expf(-sgate[0]));
        const int sur = issur[0];
#pragma unroll
        for (int b = 0; b < BB; ++b)
#pragma unroll
            for (int j = 0; j < 4; ++j) {
                float f = 0.f, mean = 0.f;
#pragma unroll
                for (int c = 0; c < CC; ++c) {
                    f = fmaf(bw[c], acc[b][j][c], f);
                    mean += acc[b][j][c];
                }
                mean *= (1.f / CC);
                float var = 0.f;
#pragma unroll
                for (int c = 0; c < CC; ++c) {
                    const float dv = acc[b][j][c] - mean;
                    var = fmaf(dv, dv, var);
                }
                var *= (1.f / (CC - 1));                 // ddof=1
                if (sur) f = fmaf(gate * var, 0.3f, f);
                fused[b * DD + e0 + j] = f;
            }
    }
}

// ---------------------------------------------------------------------------
// K4: RMS scales (per-block recompute from L2-resident fused) + out-proj GEMV.
//     128 blocks, 4 e-columns per wave.
__global__ __launch_bounds__(256) void k_rmsout(const float* __restrict__ fused,
                                                const float* __restrict__ nw,
                                                const float* __restrict__ Wo,
                                                float* __restrict__ o) {
    const int tid = threadIdx.x;
    const int lane = tid & 63, wid = tid >> 6;
    float ss[BB];
#pragma unroll
    for (int b = 0; b < BB; ++b) ss[b] = 0.f;
#pragma unroll
    for (int k = 0; k < DD / 256; ++k) {
        const int d = k * 256 + tid;
#pragma unroll
        for (int b = 0; b < BB; ++b) {
            const float v = fused[b * DD + d];
            ss[b] = fmaf(v, v, ss[b]);
        }
    }
#pragma unroll
    for (int b = 0; b < BB; ++b)
        for (int off = 32; off; off >>= 1) ss[b] += __shfl_down(ss[b], off);
    __shared__ float sred[4][BB];
    __shared__ float sscale[BB];
    if (lane == 0) {
#pragma unroll
        for (int b = 0; b < BB; ++b) sred[wid][b] = ss[b];
    }
    __syncthreads();
    if (tid == 0) {
#pragma unroll
        for (int b = 0; b < BB; ++b) {
            const float tot = sred[0][b] + sred[1][b] + sred[2][b] + sred[3][b];
            sscale[b] = rsqrtf(tot * (1.f / DD) + EPSF);
        }
    }
    __syncthreads();
    const int e0 = (blockIdx.x * 4 + wid) * 4;           // wave's 4 e-columns
    float acc[BB][4];
#pragma unroll
    for (int b = 0; b < BB; ++b)
#pragma unroll
        for (int j = 0; j < 4; ++j) acc[b][j] = 0.f;
#pragma unroll
    for (int it = 0; it < 8; ++it) {
        const int d = it * 256 + lane * 4;
        const float4 nv = *(const float4*)(nw + d);
        float4 w[4];
#pragma unroll
        for (int j = 0; j < 4; ++j) {
            const float4 wv = *(const float4*)(Wo + (size_t)(e0 + j) * DD + d);
            w[j].x = wv.x * nv.x; w[j].y = wv.y * nv.y;
            w[j].z = wv.z * nv.z; w[j].w = wv.w * nv.w;
        }
#pragma unroll
        for (int b = 0; b < BB; ++b) {
            const float4 fv = *(const float4*)(fused + (size_t)b * DD + d);
#pragma unroll
            for (int j = 0; j < 4; ++j) acc[b][j] += dot4(fv, w[j]);
        }
    }
#pragma unroll
    for (int b = 0; b < BB; ++b)
#pragma unroll
        for (int j = 0; j < 4; ++j) {
            float v = acc[b][j];
            for (int off = 32; off; off >>= 1) v += __shfl_down(v, off);
            if (lane == 0) o[b * DD + e0 + j] = v * sscale[b];
        }
}

// ---------------------------------------------------------------------------
// K5: out[b,n,e] = x[b,n,e] + o[b,e]  (nontemporal streaming, ext-vector f4)
__global__ __launch_bounds__(256) void k_add(const float* __restrict__ x,
                                             const float* __restrict__ o,
                                             float* __restrict__ out) {
    const floatx4* x4 = (const floatx4*)x;
    const floatx4* o4 = (const floatx4*)o;
    floatx4* out4 = (floatx4*)out;
    size_t f = (size_t)blockIdx.x * 256 + threadIdx.x;
#pragma unroll
    for (int k = 0; k < 8; ++k, f += (size_t)2048 * 256) {
        const int e4 = (int)(f & (DD / 4 - 1));
        const int b = (int)(f >> 21);                 // NN*DD/4 = 2^21
        const floatx4 xv = __builtin_nontemporal_load(&x4[f]);
        const floatx4 ov = o4[b * (DD / 4) + e4];
        const floatx4 r = xv + ov;
        __builtin_nontemporal_store(r, &out4[f]);
    }
}

extern "C" void kernel_launch(void* const* d_in, const int* in_sizes, int n_in,
                              void* d_out, int out_size, void* d_ws, size_t ws_size,
                              hipStream_t stream) {
    const float* x  = (const float*)d_in[0];
    const float* te = (const float*)d_in[1];
    const float* Wc = (const float*)d_in[2];
    // d_in[3] = Wq, d_in[4] = Wk : unused (softmax over a single key == 1)
    const float* Wv = (const float*)d_in[5];
    const float* Wo = (const float*)d_in[6];
    const float* bw = (const float*)d_in[7];
    const float* sg = (const float*)d_in[8];
    const float* nw = (const float*)d_in[9];
    const int* isur = (const int*)d_in[10];
    float* out = (float*)d_out;

    float* ws     = (float*)d_ws;
    float* cw     = ws;                       // B*L*C  = 3072 (pad to 4096)
    float* cr     = ws + 4096;                // B*C*D  = 24576
    float* fusedv = ws + 4096 + 24576;        // B*D    = 4096
    float* o      = fusedv + 4096;            // B*D    = 4096

    hipLaunchKernelGGL(k_cluster, dim3(BB * LL), dim3(256), 0, stream, te, Wc, cw);
    hipLaunchKernelGGL(k_creps,   dim3(BB * 32), dim3(256), 0, stream, te, cw, cr);
    hipLaunchKernelGGL(k_vfuse,   dim3(128), dim3(256), 0, stream,
                       cr, Wv, bw, sg, isur, fusedv);
    hipLaunchKernelGGL(k_rmsout,  dim3(128), dim3(256), 0, stream,
                       fusedv, nw, Wo, o);
    hipLaunchKernelGGL(k_add,     dim3(2048), dim3(256), 0, stream, x, o, out);
}

// Round 7
// 52.179 us; speedup vs baseline: 1.4121x; 1.4121x over previous
//
#include <hip/hip_runtime.h>
#include <hip/hip_bf16.h>
#include <hip/hip_cooperative_groups.h>

namespace cg = cooperative_groups;

#define BB 2
#define NN 4096
#define LL 256
#define DD 2048
#define CC 6
#define EPSF 1e-6f

__device__ __forceinline__ float dot4(float4 a, float4 b) {
    return a.x * b.x + a.y * b.y + a.z * b.z + a.w * b.w;
}

// ===========================================================================
// Cooperative front-end: phases A-D (cluster, creps, vfuse, rmsout) with
// grid.sync() between. Grid-stride over phase units -> works at ANY grid size.
__global__ __launch_bounds__(256) void k_front(
    const float* __restrict__ te, const float* __restrict__ Wc,
    const float* __restrict__ Wv, const float* __restrict__ Wo,
    const float* __restrict__ blendw, const float* __restrict__ sgate,
    const int* __restrict__ issur, const float* __restrict__ nw,
    float* __restrict__ cw, float* __restrict__ cr,
    float* __restrict__ fused, float* __restrict__ o)
{
    cg::grid_group gg = cg::this_grid();
    __shared__ float smem[3072];
    const int G = gridDim.x;
    const int tid = threadIdx.x;
    const int lane = tid & 63, wid = tid >> 6;

    //--- Phase A: cluster softmax -> cw -----------------------------------
    for (int row = blockIdx.x; row < BB * LL; row += G) {
        const float4* t4 = (const float4*)(te + (size_t)row * DD);
        float p[CC];
#pragma unroll
        for (int c = 0; c < CC; ++c) p[c] = 0.f;
#pragma unroll
        for (int it = 0; it < 2; ++it) {
            const int i = it * 256 + tid;
            const float4 xv = t4[i];
#pragma unroll
            for (int c = 0; c < CC; ++c)
                p[c] += dot4(xv, ((const float4*)(Wc + (size_t)c * DD))[i]);
        }
#pragma unroll
        for (int c = 0; c < CC; ++c)
            for (int off = 32; off; off >>= 1) p[c] += __shfl_down(p[c], off);
        if (lane == 0) {
#pragma unroll
            for (int c = 0; c < CC; ++c) smem[wid * CC + c] = p[c];
        }
        __syncthreads();
        if (tid == 0) {
            float lg[CC], m = -1e30f;
#pragma unroll
            for (int c = 0; c < CC; ++c) {
                lg[c] = smem[c] + smem[CC + c] + smem[2 * CC + c] + smem[3 * CC + c];
                m = fmaxf(m, lg[c]);
            }
            float s = 0.f;
#pragma unroll
            for (int c = 0; c < CC; ++c) { lg[c] = __expf(lg[c] - m); s += lg[c]; }
            const float inv = 1.f / s;
#pragma unroll
            for (int c = 0; c < CC; ++c) cw[row * CC + c] = lg[c] * inv;
        }
        __syncthreads();
    }
    gg.sync();

    //--- Phase B: concept_reps -> cr --------------------------------------
    for (int u = blockIdx.x; u < 64; u += G) {
        const int b = u >> 5;
        const int d0 = (u & 31) * 64;
        float* scw = smem;                   // 1536 floats
        float* sacc = smem + 1536;           // 1536 floats
        for (int i = tid; i < LL * CC; i += 256) scw[i] = cw[b * LL * CC + i];
        __syncthreads();
        float acc[CC];
#pragma unroll
        for (int c = 0; c < CC; ++c) acc[c] = 0.f;
        const float* tb = te + ((size_t)b * LL + wid * 64) * DD + d0 + lane;
        for (int l = 0; l < 64; ++l) {
            const float xv = tb[(size_t)l * DD];
            const int gl = wid * 64 + l;
#pragma unroll
            for (int c = 0; c < CC; ++c) acc[c] = fmaf(scw[gl * CC + c], xv, acc[c]);
        }
#pragma unroll
        for (int c = 0; c < CC; ++c) sacc[(wid * 64 + lane) * CC + c] = acc[c];
        __syncthreads();
        if (tid < 64) {
#pragma unroll
            for (int c = 0; c < CC; ++c) {
                const float s = sacc[(0 * 64 + tid) * CC + c] + sacc[(1 * 64 + tid) * CC + c] +
                                sacc[(2 * 64 + tid) * CC + c] + sacc[(3 * 64 + tid) * CC + c];
                cr[((size_t)b * CC + c) * DD + d0 + tid] = s;
            }
        }
        __syncthreads();
    }
    gg.sync();

    //--- Phase C: v = cr.Wv^T + blend/var fuse -> fused -------------------
    for (int u = blockIdx.x; u < 512; u += G) {
        const int e = u * 4 + wid;
        float acc[BB][CC];
#pragma unroll
        for (int b = 0; b < BB; ++b)
#pragma unroll
            for (int c = 0; c < CC; ++c) acc[b][c] = 0.f;
#pragma unroll
        for (int it = 0; it < 8; ++it) {
            const int d = it * 256 + lane * 4;
            const float4 wv = *(const float4*)(Wv + (size_t)e * DD + d);
#pragma unroll
            for (int b = 0; b < BB; ++b)
#pragma unroll
                for (int c = 0; c < CC; ++c) {
                    const float4 cv = *(const float4*)(cr + ((size_t)b * CC + c) * DD + d);
                    acc[b][c] += dot4(cv, wv);
                }
        }
#pragma unroll
        for (int b = 0; b < BB; ++b)
#pragma unroll
            for (int c = 0; c < CC; ++c)
                for (int off = 32; off; off >>= 1)
                    acc[b][c] += __shfl_down(acc[b][c], off);
        if (lane == 0) {
            float bw[CC], m = -1e30f;
#pragma unroll
            for (int c = 0; c < CC; ++c) { bw[c] = blendw[c]; m = fmaxf(m, bw[c]); }
            float s = 0.f;
#pragma unroll
            for (int c = 0; c < CC; ++c) { bw[c] = __expf(bw[c] - m); s += bw[c]; }
            const float inv = 1.f / s;
#pragma unroll
            for (int c = 0; c < CC; ++c) bw[c] *= inv;
            const float gate = 1.f / (1.f + __expf(-sgate[0]));
            const int sur = issur[0];
#pragma unroll
            for (int b = 0; b < BB; ++b) {
                float f = 0.f, mean = 0.f;
#pragma unroll
                for (int c = 0; c < CC; ++c) {
                    f = fmaf(bw[c], acc[b][c], f);
                    mean += acc[b][c];
                }
                mean *= (1.f / CC);
                float var = 0.f;
#pragma unroll
                for (int c = 0; c < CC; ++c) {
                    const float dv = acc[b][c] - mean;
                    var = fmaf(dv, dv, var);
                }
                var *= (1.f / (CC - 1));                 // ddof=1
                if (sur) f = fmaf(gate * var, 0.3f, f);
                fused[b * DD + e] = f;
            }
        }
    }
    gg.sync();

    //--- Phase D: RMS scales + out-proj GEMV -> o -------------------------
    {
        float ss[BB];
#pragma unroll
        for (int b = 0; b < BB; ++b) ss[b] = 0.f;
#pragma unroll
        for (int k = 0; k < DD / 256; ++k) {
            const int d = k * 256 + tid;
#pragma unroll
            for (int b = 0; b < BB; ++b) {
                const float v = fused[b * DD + d];
                ss[b] = fmaf(v, v, ss[b]);
            }
        }
#pragma unroll
        for (int b = 0; b < BB; ++b)
            for (int off = 32; off; off >>= 1) ss[b] += __shfl_down(ss[b], off);
        if (lane == 0) {
#pragma unroll
            for (int b = 0; b < BB; ++b) smem[wid * BB + b] = ss[b];
        }
        __syncthreads();
        if (tid == 0) {
#pragma unroll
            for (int b = 0; b < BB; ++b) {
                const float tot = smem[0 * BB + b] + smem[1 * BB + b] +
                                  smem[2 * BB + b] + smem[3 * BB + b];
                smem[8 + b] = rsqrtf(tot * (1.f / DD) + EPSF);
            }
        }
        __syncthreads();
        const float scl0 = smem[8], scl1 = smem[9];
        for (int u = blockIdx.x; u < 512; u += G) {
            const int e = u * 4 + wid;
            float acc[BB];
#pragma unroll
            for (int b = 0; b < BB; ++b) acc[b] = 0.f;
#pragma unroll
            for (int it = 0; it < 8; ++it) {
                const int d = it * 256 + lane * 4;
                const float4 wv = *(const float4*)(Wo + (size_t)e * DD + d);
                const float4 nv = *(const float4*)(nw + d);
                float4 t;
                t.x = wv.x * nv.x; t.y = wv.y * nv.y;
                t.z = wv.z * nv.z; t.w = wv.w * nv.w;
#pragma unroll
                for (int b = 0; b < BB; ++b) {
                    const float4 fv = *(const float4*)(fused + (size_t)b * DD + d);
                    acc[b] += dot4(fv, t);
                }
            }
#pragma unroll
            for (int b = 0; b < BB; ++b) {
                for (int off = 32; off; off >>= 1) acc[b] += __shfl_down(acc[b], off);
            }
            if (lane == 0) {
                o[0 * DD + e] = acc[0] * scl0;
                o[1 * DD + e] = acc[1] * scl1;
            }
        }
    }
}

// ===========================================================================
// Fallback path: verbatim R2 kernels (proven 52.2 us).
__global__ __launch_bounds__(256) void k_cluster(const float* __restrict__ te,
                                                 const float* __restrict__ Wc,
                                                 float* __restrict__ cw) {
    const int tid = threadIdx.x;
    const int row = blockIdx.x;
    const float4* t4 = (const float4*)(te + (size_t)row * DD);
    float p[CC];
#pragma unroll
    for (int c = 0; c < CC; ++c) p[c] = 0.f;
#pragma unroll
    for (int it = 0; it < 2; ++it) {
        const int i = it * 256 + tid;
        const float4 xv = t4[i];
#pragma unroll
        for (int c = 0; c < CC; ++c)
            p[c] += dot4(xv, ((const float4*)(Wc + (size_t)c * DD))[i]);
    }
#pragma unroll
    for (int c = 0; c < CC; ++c)
        for (int off = 32; off; off >>= 1) p[c] += __shfl_down(p[c], off);
    __shared__ float sred[4][CC];
    const int lane = tid & 63, wid = tid >> 6;
    if (lane == 0) {
#pragma unroll
        for (int c = 0; c < CC; ++c) sred[wid][c] = p[c];
    }
    __syncthreads();
    if (tid == 0) {
        float lg[CC], m = -1e30f;
#pragma unroll
        for (int c = 0; c < CC; ++c) {
            lg[c] = sred[0][c] + sred[1][c] + sred[2][c] + sred[3][c];
            m = fmaxf(m, lg[c]);
        }
        float s = 0.f;
#pragma unroll
        for (int c = 0; c < CC; ++c) { lg[c] = __expf(lg[c] - m); s += lg[c]; }
        const float inv = 1.f / s;
#pragma unroll
        for (int c = 0; c < CC; ++c) cw[row * CC + c] = lg[c] * inv;
    }
}

__global__ __launch_bounds__(256) void k_creps(const float* __restrict__ te,
                                               const float* __restrict__ cw,
                                               float* __restrict__ cr) {
    const int tid = threadIdx.x;
    const int b = blockIdx.x >> 5;
    const int d0 = (blockIdx.x & 31) * 64;
    const int lane = tid & 63, wid = tid >> 6;
    __shared__ float scw[LL * CC];
    __shared__ float sacc[4][64][CC];
    for (int i = tid; i < LL * CC; i += 256) scw[i] = cw[b * LL * CC + i];
    __syncthreads();
    float acc[CC];
#pragma unroll
    for (int c = 0; c < CC; ++c) acc[c] = 0.f;
    const float* tb = te + ((size_t)b * LL + wid * 64) * DD + d0 + lane;
    for (int l = 0; l < 64; ++l) {
        const float xv = tb[(size_t)l * DD];
        const int gl = wid * 64 + l;
#pragma unroll
        for (int c = 0; c < CC; ++c) acc[c] = fmaf(scw[gl * CC + c], xv, acc[c]);
    }
#pragma unroll
    for (int c = 0; c < CC; ++c) sacc[wid][lane][c] = acc[c];
    __syncthreads();
    if (tid < 64) {
#pragma unroll
        for (int c = 0; c < CC; ++c) {
            const float s = sacc[0][tid][c] + sacc[1][tid][c] +
                            sacc[2][tid][c] + sacc[3][tid][c];
            cr[((size_t)b * CC + c) * DD + d0 + tid] = s;
        }
    }
}

__global__ __launch_bounds__(256) void k_vfuse(const float* __restrict__ cr,
                                               const float* __restrict__ Wv,
                                               const float* __restrict__ blendw,
                                               const float* __restrict__ sgate,
                                               const int* __restrict__ issur,
                                               float* __restrict__ fused) {
    const int tid = threadIdx.x;
    const int lane = tid & 63, wid = tid >> 6;
    const int e = blockIdx.x * 4 + wid;
    float acc[BB][CC];
#pragma unroll
    for (int b = 0; b < BB; ++b)
#pragma unroll
        for (int c = 0; c < CC; ++c) acc[b][c] = 0.f;
#pragma unroll
    for (int it = 0; it < 8; ++it) {
        const int d = it * 256 + lane * 4;
        const float4 wv = *(const float4*)(Wv + (size_t)e * DD + d);
#pragma unroll
        for (int b = 0; b < BB; ++b)
#pragma unroll
            for (int c = 0; c < CC; ++c) {
                const float4 cv = *(const float4*)(cr + ((size_t)b * CC + c) * DD + d);
                acc[b][c] += dot4(cv, wv);
            }
    }
#pragma unroll
    for (int b = 0; b < BB; ++b)
#pragma unroll
        for (int c = 0; c < CC; ++c)
            for (int off = 32; off; off >>= 1)
                acc[b][c] += __shfl_down(acc[b][c], off);
    if (lane == 0) {
        float bw[CC], m = -1e30f;
#pragma unroll
        for (int c = 0; c < CC; ++c) { bw[c] = blendw[c]; m = fmaxf(m, bw[c]); }
        float s = 0.f;
#pragma unroll
        for (int c = 0; c < CC; ++c) { bw[c] = __expf(bw[c] - m); s += bw[c]; }
        const float inv = 1.f / s;
#pragma unroll
        for (int c = 0; c < CC; ++c) bw[c] *= inv;
        const float gate = 1.f / (1.f + __expf(-sgate[0]));
        const int sur = issur[0];
#pragma unroll
        for (int b = 0; b < BB; ++b) {
            float f = 0.f, mean = 0.f;
#pragma unroll
            for (int c = 0; c < CC; ++c) {
                f = fmaf(bw[c], acc[b][c], f);
                mean += acc[b][c];
            }
            mean *= (1.f / CC);
            float var = 0.f;
#pragma unroll
            for (int c = 0; c < CC; ++c) {
                const float dv = acc[b][c] - mean;
                var = fmaf(dv, dv, var);
            }
            var *= (1.f / (CC - 1));
            if (sur) f = fmaf(gate * var, 0.3f, f);
            fused[b * DD + e] = f;
        }
    }
}

__global__ __launch_bounds__(256) void k_rmsout(const float* __restrict__ fused,
                                                const float* __restrict__ nw,
                                                const float* __restrict__ Wo,
                                                float* __restrict__ o) {
    const int tid = threadIdx.x;
    const int lane = tid & 63, wid = tid >> 6;
    float ss[BB];
#pragma unroll
    for (int b = 0; b < BB; ++b) ss[b] = 0.f;
#pragma unroll
    for (int k = 0; k < DD / 256; ++k) {
        const int d = k * 256 + tid;
#pragma unroll
        for (int b = 0; b < BB; ++b) {
            const float v = fused[b * DD + d];
            ss[b] = fmaf(v, v, ss[b]);
        }
    }
#pragma unroll
    for (int b = 0; b < BB; ++b)
        for (int off = 32; off; off >>= 1) ss[b] += __shfl_down(ss[b], off);
    __shared__ float sred[4][BB];
    __shared__ float sscale[BB];
    if (lane == 0) {
#pragma unroll
        for (int b = 0; b < BB; ++b) sred[wid][b] = ss[b];
    }
    __syncthreads();
    if (tid == 0) {
#pragma unroll
        for (int b = 0; b < BB; ++b) {
            const float tot = sred[0][b] + sred[1][b] + sred[2][b] + sred[3][b];
            sscale[b] = rsqrtf(tot * (1.f / DD) + EPSF);
        }
    }
    __syncthreads();
    const int e = blockIdx.x * 4 + wid;
    float acc[BB];
#pragma unroll
    for (int b = 0; b < BB; ++b) acc[b] = 0.f;
#pragma unroll
    for (int it = 0; it < 8; ++it) {
        const int d = it * 256 + lane * 4;
        const float4 wv = *(const float4*)(Wo + (size_t)e * DD + d);
        const float4 nv = *(const float4*)(nw + d);
        float4 t;
        t.x = wv.x * nv.x; t.y = wv.y * nv.y; t.z = wv.z * nv.z; t.w = wv.w * nv.w;
#pragma unroll
        for (int b = 0; b < BB; ++b) {
            const float4 fv = *(const float4*)(fused + (size_t)b * DD + d);
            acc[b] += dot4(fv, t);
        }
    }
#pragma unroll
    for (int b = 0; b < BB; ++b) {
        for (int off = 32; off; off >>= 1) acc[b] += __shfl_down(acc[b], off);
        if (lane == 0) o[b * DD + e] = acc[b] * sscale[b];
    }
}

// ===========================================================================
// Final broadcast-add (R2-verbatim, proven).
__global__ __launch_bounds__(256) void k_add(const float* __restrict__ x,
                                             const float* __restrict__ o,
                                             float* __restrict__ out) {
    const size_t total4 = (size_t)BB * NN * DD / 4;   // 2^22
    const float4* x4 = (const float4*)x;
    const float4* o4 = (const float4*)o;
    float4* out4 = (float4*)out;
    for (size_t f = (size_t)blockIdx.x * 256 + threadIdx.x; f < total4;
         f += (size_t)gridDim.x * 256) {
        const int e4 = (int)(f & (DD / 4 - 1));
        const int b = (int)(f >> 21);                 // NN*DD/4 = 2^21
        const float4 xv = x4[f];
        const float4 ov = o4[b * (DD / 4) + e4];
        float4 r;
        r.x = xv.x + ov.x; r.y = xv.y + ov.y;
        r.z = xv.z + ov.z; r.w = xv.w + ov.w;
        out4[f] = r;
    }
}

extern "C" void kernel_launch(void* const* d_in, const int* in_sizes, int n_in,
                              void* d_out, int out_size, void* d_ws, size_t ws_size,
                              hipStream_t stream) {
    const float* x  = (const float*)d_in[0];
    const float* te = (const float*)d_in[1];
    const float* Wc = (const float*)d_in[2];
    // d_in[3] = Wq, d_in[4] = Wk : unused (softmax over a single key == 1)
    const float* Wv = (const float*)d_in[5];
    const float* Wo = (const float*)d_in[6];
    const float* bw = (const float*)d_in[7];
    const float* sg = (const float*)d_in[8];
    const float* nw = (const float*)d_in[9];
    const int* isur = (const int*)d_in[10];
    float* out = (float*)d_out;

    float* ws     = (float*)d_ws;
    float* cw     = ws;                       // B*L*C  = 3072 (pad to 4096)
    float* cr     = ws + 4096;                // B*C*D  = 24576
    float* fusedv = ws + 4096 + 24576;        // B*D    = 4096
    float* o      = fusedv + 4096;            // B*D    = 4096

    // --- try cooperative front-end (A-D fused), fallback to 4 kernels ---
    bool launched = false;
    int nbPerCU = 0;
    hipError_t qe = hipOccupancyMaxActiveBlocksPerMultiprocessor(
        &nbPerCU, (const void*)k_front, 256, 0);
    if (qe == hipSuccess && nbPerCU > 0) {
        long total = (long)nbPerCU * 256;     // 256 CUs on MI355X
        int grid = (int)(total < 512 ? total : 512);
        void* args[] = { (void*)&te, (void*)&Wc, (void*)&Wv, (void*)&Wo,
                         (void*)&bw, (void*)&sg, (void*)&isur, (void*)&nw,
                         (void*)&cw, (void*)&cr, (void*)&fusedv, (void*)&o };
        hipError_t le = hipLaunchCooperativeKernel((void*)k_front, dim3(grid),
                                                   dim3(256), args, 0, stream);
        if (le == hipSuccess) launched = true;
        else (void)hipGetLastError();         // clear sticky error
    } else {
        (void)hipGetLastError();
    }
    if (!launched) {
        hipLaunchKernelGGL(k_cluster, dim3(BB * LL), dim3(256), 0, stream, te, Wc, cw);
        hipLaunchKernelGGL(k_creps,   dim3(BB * 32), dim3(256), 0, stream, te, cw, cr);
        hipLaunchKernelGGL(k_vfuse,   dim3(DD / 4), dim3(256), 0, stream,
                           cr, Wv, bw, sg, isur, fusedv);
        hipLaunchKernelGGL(k_rmsout,  dim3(DD / 4), dim3(256), 0, stream,
                           fusedv, nw, Wo, o);
    }
    hipLaunchKernelGGL(k_add, dim3(2048), dim3(256), 0, stream, x, o, out);
}

// Round 8
// 50.882 us; speedup vs baseline: 1.4481x; 1.0255x over previous
//
#include <hip/hip_runtime.h>
#include <hip/hip_bf16.h>

#define BB 2
#define NN 4096
#define LL 256
#define DD 2048
#define CC 6
#define EPSF 1e-6f

typedef float floatx4 __attribute__((ext_vector_type(4)));

__device__ __forceinline__ float dot4(float4 a, float4 b) {
    return a.x * b.x + a.y * b.y + a.z * b.z + a.w * b.w;
}

// ---------------------------------------------------------------------------
// K1: cluster softmax -> cw (B,L,C). One block per (b,l) row. (R2-proven)
__global__ __launch_bounds__(256) void k_cluster(const float* __restrict__ te,
                                                 const float* __restrict__ Wc,
                                                 float* __restrict__ cw) {
    const int tid = threadIdx.x;
    const int row = blockIdx.x;              // b*LL + l
    const float4* t4 = (const float4*)(te + (size_t)row * DD);
    float p[CC];
#pragma unroll
    for (int c = 0; c < CC; ++c) p[c] = 0.f;
#pragma unroll
    for (int it = 0; it < 2; ++it) {
        const int i = it * 256 + tid;
        const float4 xv = t4[i];
#pragma unroll
        for (int c = 0; c < CC; ++c)
            p[c] += dot4(xv, ((const float4*)(Wc + (size_t)c * DD))[i]);
    }
#pragma unroll
    for (int c = 0; c < CC; ++c)
        for (int off = 32; off; off >>= 1) p[c] += __shfl_down(p[c], off);
    __shared__ float sred[4][CC];
    const int lane = tid & 63, wid = tid >> 6;
    if (lane == 0) {
#pragma unroll
        for (int c = 0; c < CC; ++c) sred[wid][c] = p[c];
    }
    __syncthreads();
    if (tid == 0) {
        float lg[CC], m = -1e30f;
#pragma unroll
        for (int c = 0; c < CC; ++c) {
            lg[c] = sred[0][c] + sred[1][c] + sred[2][c] + sred[3][c];
            m = fmaxf(m, lg[c]);
        }
        float s = 0.f;
#pragma unroll
        for (int c = 0; c < CC; ++c) { lg[c] = __expf(lg[c] - m); s += lg[c]; }
        const float inv = 1.f / s;
#pragma unroll
        for (int c = 0; c < CC; ++c) cw[row * CC + c] = lg[c] * inv;
    }
}

// ---------------------------------------------------------------------------
// K2: concept_reps -> cr (B,C,D). 128 blocks; block = (b, 32-wide d-slice),
//     8 l-chunks of 32 across the block, LDS reduce.
__global__ __launch_bounds__(256) void k_creps(const float* __restrict__ te,
                                               const float* __restrict__ cw,
                                               float* __restrict__ cr) {
    const int tid = threadIdx.x;
    const int b = blockIdx.x >> 6;
    const int d0 = (blockIdx.x & 63) * 32;
    const int dl = tid & 31;                 // d within slice
    const int lc = tid >> 5;                 // l-chunk 0..7
    __shared__ float scw[LL * CC];           // 6 KB
    __shared__ float sacc[8][32][CC];        // 6 KB
    for (int i = tid; i < LL * CC; i += 256) scw[i] = cw[b * LL * CC + i];
    __syncthreads();
    float acc[CC];
#pragma unroll
    for (int c = 0; c < CC; ++c) acc[c] = 0.f;
    const float* tb = te + ((size_t)b * LL + lc * 32) * DD + d0 + dl;
    for (int l = 0; l < 32; ++l) {
        const float xv = tb[(size_t)l * DD];
        const int gl = lc * 32 + l;
#pragma unroll
        for (int c = 0; c < CC; ++c) acc[c] = fmaf(scw[gl * CC + c], xv, acc[c]);
    }
#pragma unroll
    for (int c = 0; c < CC; ++c) sacc[lc][dl][c] = acc[c];
    __syncthreads();
    if (tid < 32) {
#pragma unroll
        for (int c = 0; c < CC; ++c) {
            float s = 0.f;
#pragma unroll
            for (int k = 0; k < 8; ++k) s += sacc[k][tid][c];
            cr[((size_t)b * CC + c) * DD + d0 + tid] = s;
        }
    }
}

// ---------------------------------------------------------------------------
// K3: v = cr.Wv^T + blend-softmax + unbiased-var gate -> fused (B,D).
//     512 blocks; wave = (pair p, half h): 2 e-columns over half of D.
//     Halves combined in LDS -> cr L2 traffic halved at full 2-blocks/CU.
__global__ __launch_bounds__(256) void k_vfuse(const float* __restrict__ cr,
                                               const float* __restrict__ Wv,
                                               const float* __restrict__ blendw,
                                               const float* __restrict__ sgate,
                                               const int* __restrict__ issur,
                                               float* __restrict__ fused) {
    const int tid = threadIdx.x;
    const int lane = tid & 63, wid = tid >> 6;
    const int p = wid >> 1, h = wid & 1;
    const int e0 = blockIdx.x * 4 + p * 2;   // this pair's 2 e-columns
    float acc[BB][2][CC];
#pragma unroll
    for (int b = 0; b < BB; ++b)
#pragma unroll
        for (int j = 0; j < 2; ++j)
#pragma unroll
            for (int c = 0; c < CC; ++c) acc[b][j][c] = 0.f;
#pragma unroll
    for (int it = 0; it < 4; ++it) {
        const int d = h * 1024 + it * 256 + lane * 4;
        const float4 w0 = *(const float4*)(Wv + (size_t)e0 * DD + d);
        const float4 w1 = *(const float4*)(Wv + (size_t)(e0 + 1) * DD + d);
#pragma unroll
        for (int b = 0; b < BB; ++b)
#pragma unroll
            for (int c = 0; c < CC; ++c) {
                const float4 cv = *(const float4*)(cr + ((size_t)b * CC + c) * DD + d);
                acc[b][0][c] += dot4(cv, w0);
                acc[b][1][c] += dot4(cv, w1);
            }
    }
#pragma unroll
    for (int b = 0; b < BB; ++b)
#pragma unroll
        for (int j = 0; j < 2; ++j)
#pragma unroll
            for (int c = 0; c < CC; ++c)
                for (int off = 32; off; off >>= 1)
                    acc[b][j][c] += __shfl_down(acc[b][j][c], off);
    __shared__ float sred[2][2][BB][2][CC];
    if (lane == 0) {
#pragma unroll
        for (int b = 0; b < BB; ++b)
#pragma unroll
            for (int j = 0; j < 2; ++j)
#pragma unroll
                for (int c = 0; c < CC; ++c) sred[p][h][b][j][c] = acc[b][j][c];
    }
    __syncthreads();
    if (h == 0 && lane == 0) {
        float bw[CC], m = -1e30f;
#pragma unroll
        for (int c = 0; c < CC; ++c) { bw[c] = blendw[c]; m = fmaxf(m, bw[c]); }
        float s = 0.f;
#pragma unroll
        for (int c = 0; c < CC; ++c) { bw[c] = __expf(bw[c] - m); s += bw[c]; }
        const float inv = 1.f / s;
#pragma unroll
        for (int c = 0; c < CC; ++c) bw[c] *= inv;
        const float gate = 1.f / (1.f + __expf(-sgate[0]));
        const int sur = issur[0];
#pragma unroll
        for (int b = 0; b < BB; ++b)
#pragma unroll
            for (int j = 0; j < 2; ++j) {
                float vv[CC];
#pragma unroll
                for (int c = 0; c < CC; ++c)
                    vv[c] = sred[p][0][b][j][c] + sred[p][1][b][j][c];
                float f = 0.f, mean = 0.f;
#pragma unroll
                for (int c = 0; c < CC; ++c) { f = fmaf(bw[c], vv[c], f); mean += vv[c]; }
                mean *= (1.f / CC);
                float var = 0.f;
#pragma unroll
                for (int c = 0; c < CC; ++c) {
                    const float dv = vv[c] - mean;
                    var = fmaf(dv, dv, var);
                }
                var *= (1.f / (CC - 1));     // ddof=1
                if (sur) f = fmaf(gate * var, 0.3f, f);
                fused[b * DD + e0 + j] = f;
            }
    }
}

// ---------------------------------------------------------------------------
// K4: RMS scales (per-block recompute) + out-proj GEMV. Same split-D layout.
__global__ __launch_bounds__(256) void k_rmsout(const float* __restrict__ fused,
                                                const float* __restrict__ nw,
                                                const float* __restrict__ Wo,
                                                float* __restrict__ o) {
    const int tid = threadIdx.x;
    const int lane = tid & 63, wid = tid >> 6;
    float ss[BB];
#pragma unroll
    for (int b = 0; b < BB; ++b) ss[b] = 0.f;
#pragma unroll
    for (int k = 0; k < DD / 256; ++k) {
        const int d = k * 256 + tid;
#pragma unroll
        for (int b = 0; b < BB; ++b) {
            const float v = fused[b * DD + d];
            ss[b] = fmaf(v, v, ss[b]);
        }
    }
#pragma unroll
    for (int b = 0; b < BB; ++b)
        for (int off = 32; off; off >>= 1) ss[b] += __shfl_down(ss[b], off);
    __shared__ float sred0[4][BB];
    __shared__ float sscale[BB];
    if (lane == 0) {
#pragma unroll
        for (int b = 0; b < BB; ++b) sred0[wid][b] = ss[b];
    }
    __syncthreads();
    if (tid == 0) {
#pragma unroll
        for (int b = 0; b < BB; ++b) {
            const float tot = sred0[0][b] + sred0[1][b] + sred0[2][b] + sred0[3][b];
            sscale[b] = rsqrtf(tot * (1.f / DD) + EPSF);
        }
    }
    __syncthreads();
    const int p = wid >> 1, h = wid & 1;
    const int e0 = blockIdx.x * 4 + p * 2;
    float acc[BB][2];
#pragma unroll
    for (int b = 0; b < BB; ++b)
#pragma unroll
        for (int j = 0; j < 2; ++j) acc[b][j] = 0.f;
#pragma unroll
    for (int it = 0; it < 4; ++it) {
        const int d = h * 1024 + it * 256 + lane * 4;
        const float4 nv = *(const float4*)(nw + d);
        float4 w0 = *(const float4*)(Wo + (size_t)e0 * DD + d);
        float4 w1 = *(const float4*)(Wo + (size_t)(e0 + 1) * DD + d);
        w0.x *= nv.x; w0.y *= nv.y; w0.z *= nv.z; w0.w *= nv.w;
        w1.x *= nv.x; w1.y *= nv.y; w1.z *= nv.z; w1.w *= nv.w;
#pragma unroll
        for (int b = 0; b < BB; ++b) {
            const float4 fv = *(const float4*)(fused + (size_t)b * DD + d);
            acc[b][0] += dot4(fv, w0);
            acc[b][1] += dot4(fv, w1);
        }
    }
#pragma unroll
    for (int b = 0; b < BB; ++b)
#pragma unroll
        for (int j = 0; j < 2; ++j)
            for (int off = 32; off; off >>= 1) acc[b][j] += __shfl_down(acc[b][j], off);
    __shared__ float sred1[2][2][BB][2];
    if (lane == 0) {
#pragma unroll
        for (int b = 0; b < BB; ++b)
#pragma unroll
            for (int j = 0; j < 2; ++j) sred1[p][h][b][j] = acc[b][j];
    }
    __syncthreads();
    if (h == 0 && lane == 0) {
#pragma unroll
        for (int b = 0; b < BB; ++b)
#pragma unroll
            for (int j = 0; j < 2; ++j)
                o[b * DD + e0 + j] = (sred1[p][0][b][j] + sred1[p][1][b][j]) * sscale[b];
    }
}

// ---------------------------------------------------------------------------
// K5: out[b,n,e] = x[b,n,e] + o[b,e].
//     x load CACHEABLE (L3-resident across replays); out store NONTEMPORAL
//     (write-once stream; avoid evicting x/Wv/Wo from L3 between replays).
__global__ __launch_bounds__(256) void k_add(const float* __restrict__ x,
                                             const float* __restrict__ o,
                                             float* __restrict__ out) {
    const size_t total4 = (size_t)BB * NN * DD / 4;   // 2^22
    const floatx4* x4 = (const floatx4*)x;
    const floatx4* o4 = (const floatx4*)o;
    floatx4* out4 = (floatx4*)out;
    for (size_t f = (size_t)blockIdx.x * 256 + threadIdx.x; f < total4;
         f += (size_t)2048 * 256) {
        const int e4 = (int)(f & (DD / 4 - 1));
        const int b = (int)(f >> 21);                 // NN*DD/4 = 2^21
        const floatx4 xv = x4[f];                     // cacheable read
        const floatx4 ov = o4[b * (DD / 4) + e4];
        const floatx4 r = xv + ov;
        __builtin_nontemporal_store(r, &out4[f]);     // streaming write
    }
}

extern "C" void kernel_launch(void* const* d_in, const int* in_sizes, int n_in,
                              void* d_out, int out_size, void* d_ws, size_t ws_size,
                              hipStream_t stream) {
    const float* x  = (const float*)d_in[0];
    const float* te = (const float*)d_in[1];
    const float* Wc = (const float*)d_in[2];
    // d_in[3] = Wq, d_in[4] = Wk : unused (softmax over a single key == 1)
    const float* Wv = (const float*)d_in[5];
    const float* Wo = (const float*)d_in[6];
    const float* bw = (const float*)d_in[7];
    const float* sg = (const float*)d_in[8];
    const float* nw = (const float*)d_in[9];
    const int* isur = (const int*)d_in[10];
    float* out = (float*)d_out;

    float* ws     = (float*)d_ws;
    float* cw     = ws;                       // B*L*C  = 3072 (pad to 4096)
    float* cr     = ws + 4096;                // B*C*D  = 24576
    float* fusedv = ws + 4096 + 24576;        // B*D    = 4096
    float* o      = fusedv + 4096;            // B*D    = 4096

    hipLaunchKernelGGL(k_cluster, dim3(BB * LL), dim3(256), 0, stream, te, Wc, cw);
    hipLaunchKernelGGL(k_creps,   dim3(BB * 64), dim3(256), 0, stream, te, cw, cr);
    hipLaunchKernelGGL(k_vfuse,   dim3(DD / 4), dim3(256), 0, stream,
                       cr, Wv, bw, sg, isur, fusedv);
    hipLaunchKernelGGL(k_rmsout,  dim3(DD / 4), dim3(256), 0, stream,
                       fusedv, nw, Wo, o);
    hipLaunchKernelGGL(k_add,     dim3(2048), dim3(256), 0, stream, x, o, out);
}